// Round 5
// baseline (326.818 us; speedup 1.0000x reference)
//
#include <hip/hip_runtime.h>
#include <hip/hip_fp16.h>
#include <math.h>

#define LUT_D 33
#define LUT_D3 35937   // 33^3
#define NEG 0.2f
#define BATCH 4
#define HW_IMG 1048576 // 1024*1024

// ---------------- fused conv3x3 s2 p1 + LeakyReLU + (input-norm | input-resize) ------------
// block = (b, ty, tx, ocg); 256 threads = 64 px * 4 oc-lanes (4 oc each).
// IC processed in chunks of ICCH (stage weights+input per chunk, accumulate in regs).
// NORM_IN: per-block recompute of (sc,sh) InstanceNorm pairs from producer's part stats
//          (redundant across blocks, but removes a kernel launch + tiny k_norm dispatch).
// RESIZE_IN: input = lq 1024x1024; staged pixels computed as the 4->1 bilinear tap
//            0.25*(lq[4y+1,4x+1..2]+lq[4y+2,4x+1..2]) via 16B-aligned float4 at col 4x.
// STATS_OUT: per-(oc,tile) wave partial sums of activated outputs -> part_out.
template<int IC, int OC, int OH, int OW, int ICCH, bool NORM_IN, bool RESIZE_IN, bool STATS_OUT>
__global__ void __launch_bounds__(256) k_conv2(
    const float* __restrict__ in, const float* __restrict__ part_in,
    const float* __restrict__ g, const float* __restrict__ be, float invN, int ntin,
    const float* __restrict__ w, const float* __restrict__ bias,
    float* __restrict__ out, float* __restrict__ part_out) {
    constexpr int IH = OH * 2, IW = OW * 2;
    constexpr int NCH = IC / ICCH;
    constexpr int TROW = 20, TSZ = 17 * TROW;     // 340 floats per ic tile
    constexpr int NTX = OW / 8, NTY = OH / 8, NOCG = OC / 16;
    constexpr int NT = NTX * NTY;

    __shared__ float sIn[ICCH * TSZ];
    __shared__ float swl[16 * ICCH * 9];
    __shared__ float sNm[NORM_IN ? IC * 2 : 1];

    int id = blockIdx.x;
    int ocg = id % NOCG;  id /= NOCG;
    int tx  = id % NTX;   id /= NTX;
    int ty  = id % NTY;   id /= NTY;
    int b   = id;

    int t    = threadIdx.x;
    int lane = t >> 6;          // 0..3
    int px   = t & 63;
    int py   = px >> 3, pxx = px & 7;
    int oc0  = ocg * 16 + lane * 4;

    // ---- fused InstanceNorm pair computation (all IC channels) ----
    if (NORM_IN) {
        constexpr int P = 256 / IC;             // threads per channel (2..16)
        int c = t / P, r = t % P;
        float s1 = 0.f, s2 = 0.f;
        for (int i = r; i < ntin; i += P) {
            const float* pp = part_in + ((size_t)(b * IC + c) * ntin + i) * 2;
            s1 += pp[0]; s2 += pp[1];
        }
        #pragma unroll
        for (int off = P >> 1; off > 0; off >>= 1) {
            s1 += __shfl_down(s1, off, 64);
            s2 += __shfl_down(s2, off, 64);
        }
        if (r == 0) {
            float m   = s1 * invN;
            float var = s2 * invN - m * m;
            float sc  = g[c] * rsqrtf(var + 1e-5f);
            sNm[c * 2]     = sc;
            sNm[c * 2 + 1] = be[c] - m * sc;
        }
        __syncthreads();
    }

    float acc[4];
    #pragma unroll
    for (int j = 0; j < 4; j++) acc[j] = bias[oc0 + j];

    int iy0 = ty * 16 - 1;
    int xbase = tx * 16;

    for (int ch = 0; ch < NCH; ch++) {
        int icc = ch * ICCH;
        if (ch) __syncthreads();                // protect LDS from previous chunk's compute

        // ---- stage weights for this chunk ----
        if (IC == ICCH) {
            const float4* wsrc = (const float4*)(w + (size_t)ocg * 16 * IC * 9);
            for (int i = t; i < 16 * IC * 9 / 4; i += 256) ((float4*)swl)[i] = wsrc[i];
        } else {
            constexpr int WQ = ICCH * 9 / 4;    // ICCH in {16,32} -> integer
            for (int i = t; i < 16 * WQ; i += 256) {
                int ol = i / WQ, qi = i % WQ;
                ((float4*)swl)[ol * WQ + qi] =
                    *(const float4*)(w + ((size_t)(ocg * 16 + ol) * IC + icc) * 9 + qi * 4);
            }
        }

        // ---- stage input tile ----
        if (RESIZE_IN) {
            for (int q = t; q < ICCH * 17 * 4; q += 256) {
                int ic_l = q / 68;
                int r2   = q % 68;
                int row  = r2 >> 2, quad = r2 & 3;
                int iy = iy0 + row;
                float4 v = {0.f, 0.f, 0.f, 0.f};
                if (iy >= 0 && iy < IH) {
                    const float* lb_ = in + (size_t)(b * IC + icc + ic_l) * HW_IMG
                                          + (size_t)(4 * iy + 1) * 1024;
                    int c0 = (xbase + quad * 4) * 4;          // 16B-aligned
                    const float4* pa = (const float4*)(lb_ + c0);
                    const float4* pb = (const float4*)(lb_ + 1024 + c0);
                    float4 a0 = pa[0], a1 = pa[1], a2 = pa[2], a3 = pa[3];
                    float4 q0 = pb[0], q1 = pb[1], q2 = pb[2], q3 = pb[3];
                    v.x = 0.25f * (a0.y + a0.z + q0.y + q0.z);
                    v.y = 0.25f * (a1.y + a1.z + q1.y + q1.z);
                    v.z = 0.25f * (a2.y + a2.z + q2.y + q2.z);
                    v.w = 0.25f * (a3.y + a3.z + q3.y + q3.z);
                }
                *(float4*)(sIn + ic_l * TSZ + row * TROW + 4 + quad * 4) = v;
            }
            for (int h = t; h < ICCH * 17; h += 256) {
                int ic_l = h / 17, row = h % 17;
                int iy = iy0 + row, ix = xbase - 1;
                float v = 0.f;
                if (iy >= 0 && iy < IH && ix >= 0) {
                    const float* lb_ = in + (size_t)(b * IC + icc + ic_l) * HW_IMG
                                          + (size_t)(4 * iy + 1) * 1024;
                    float4 a = *(const float4*)(lb_ + ix * 4);
                    float4 q0 = *(const float4*)(lb_ + 1024 + ix * 4);
                    v = 0.25f * (a.y + a.z + q0.y + q0.z);
                }
                sIn[ic_l * TSZ + row * TROW + 3] = v;
            }
        } else {
            const float* inb = in + (size_t)(b * IC + icc) * (IH * IW);
            for (int q = t; q < ICCH * 17 * 4; q += 256) {
                int ic_l = q / 68;
                int r2   = q % 68;
                int row  = r2 >> 2, quad = r2 & 3;
                int iy = iy0 + row;
                float4 v = {0.f, 0.f, 0.f, 0.f};
                if (iy >= 0 && iy < IH) {
                    v = *(const float4*)(inb + (size_t)ic_l * (IH * IW)
                                             + (size_t)iy * IW + xbase + quad * 4);
                    if (NORM_IN) {
                        float sc = sNm[(icc + ic_l) * 2], sh = sNm[(icc + ic_l) * 2 + 1];
                        v.x = v.x * sc + sh; v.y = v.y * sc + sh;
                        v.z = v.z * sc + sh; v.w = v.w * sc + sh;
                    }
                }
                *(float4*)(sIn + ic_l * TSZ + row * TROW + 4 + quad * 4) = v;
            }
            for (int h = t; h < ICCH * 17; h += 256) {
                int ic_l = h / 17, row = h % 17;
                int iy = iy0 + row, ix = xbase - 1;
                float v = 0.f;
                if (iy >= 0 && iy < IH && ix >= 0) {
                    v = inb[(size_t)ic_l * (IH * IW) + (size_t)iy * IW + ix];
                    if (NORM_IN) v = v * sNm[(icc + ic_l) * 2] + sNm[(icc + ic_l) * 2 + 1];
                }
                sIn[ic_l * TSZ + row * TROW + 3] = v;
            }
        }
        __syncthreads();

        // ---- compute chunk ----
        for (int i2 = 0; i2 < ICCH; i2++) {
            const float* tp = sIn + i2 * TSZ + py * 2 * TROW + pxx * 2 + 3;
            float x0 = tp[0],        x1 = tp[1],        x2 = tp[2];
            float x3 = tp[TROW],     x4 = tp[TROW + 1], x5 = tp[TROW + 2];
            float x6 = tp[2 * TROW], x7 = tp[2 * TROW + 1], x8 = tp[2 * TROW + 2];
            #pragma unroll
            for (int j = 0; j < 4; j++) {
                const float* wp = swl + ((lane * 4 + j) * ICCH + i2) * 9;
                acc[j] = fmaf(x0, wp[0], acc[j]);
                acc[j] = fmaf(x1, wp[1], acc[j]);
                acc[j] = fmaf(x2, wp[2], acc[j]);
                acc[j] = fmaf(x3, wp[3], acc[j]);
                acc[j] = fmaf(x4, wp[4], acc[j]);
                acc[j] = fmaf(x5, wp[5], acc[j]);
                acc[j] = fmaf(x6, wp[6], acc[j]);
                acc[j] = fmaf(x7, wp[7], acc[j]);
                acc[j] = fmaf(x8, wp[8], acc[j]);
            }
        }
    }

    // ---- epilogue: LeakyReLU, store, optional stats ----
    int oy = ty * 8 + py, ox = tx * 8 + pxx;
    int tile = ty * NTX + tx;
    #pragma unroll
    for (int j = 0; j < 4; j++) {
        float a = acc[j];
        a = a >= 0.f ? a : NEG * a;
        out[((size_t)(b * OC + oc0 + j) * OH + oy) * OW + ox] = a;
        if (STATS_OUT) {
            float s1 = a, s2 = a * a;
            for (int off = 32; off > 0; off >>= 1) {
                s1 += __shfl_down(s1, off, 64);
                s2 += __shfl_down(s2, off, 64);
            }
            if (px == 0) {
                size_t pi = ((size_t)(b * OC + oc0 + j) * NT + tile) * 2;
                part_out[pi] = s1; part_out[pi + 1] = s2;
            }
        }
    }
}

// ---------------- head: pool(f5) -> codes; weights; vertices; 5-float search table --------
// Table per (b,ch), 256 bins u (x*2^8 exact): entry {vs, m0, c0, m1, c1} at stride 5:
//   coord = (x < vs) ? m0*x+c0 : m1*x+c1   (exact when <=1 interior vertex per bin;
//   >=2 interior -> m0=NaN marker -> transform binary-search fallback).
__global__ void k_head(const float* __restrict__ f5, const float* __restrict__ lw,
                       const float* __restrict__ lb, const float* __restrict__ aw,
                       const float* __restrict__ ab, float* __restrict__ wt,
                       float* __restrict__ vert, float* __restrict__ gT,
                       float* __restrict__ out_w, float* __restrict__ out_v) {
    int blk = blockIdx.x;
    int t = threadIdx.x;  // 64 threads
    if (blk == 12) {
        __shared__ float sc2[2048];
        for (int s = t; s < 2048; s += 64) {
            int b = s >> 9, rest = s & 511, oc = rest >> 2, q = rest & 3;
            int py = (q >> 1) * 4, pxq = (q & 1) * 4;
            const float* p = f5 + (size_t)(b * 128 + oc) * 64;
            float sum = 0.f;
            #pragma unroll
            for (int dy = 0; dy < 4; dy++) {
                float4 v = *(const float4*)(p + (py + dy) * 8 + pxq);
                sum += v.x + v.y + v.z + v.w;
            }
            sc2[s] = sum * (1.f / 16.f);
        }
        __syncthreads();
        if (t < 48) {
            int j = t >> 2, q = t & 3;          // 12 outputs x 4 threads
            int b = j / 3, jj = j % 3;
            const float4* c4 = (const float4*)(sc2 + b * 512 + q * 128);
            const float4* l4 = (const float4*)(lw + jj * 512 + q * 128);
            float s = 0.f;
            for (int k = 0; k < 32; k++) {
                float4 cv = c4[k], lv = l4[k];
                s += cv.x * lv.x + cv.y * lv.y + cv.z * lv.z + cv.w * lv.w;
            }
            s += __shfl_down(s, 2, 64);
            s += __shfl_down(s, 1, 64);
            if (q == 0) { s += lb[jj]; wt[j] = s; out_w[j] = s; }
        }
        return;
    }
    int b = blk / 3, ch = blk % 3;
    __shared__ float scode[512];
    __shared__ float y[32];
    __shared__ float vsh[33];
    for (int s = t; s < 512; s += 64) {
        int oc = s >> 2, q = s & 3;
        int py = (q >> 1) * 4, pxq = (q & 1) * 4;
        const float* p = f5 + (size_t)(b * 128 + oc) * 64;
        float sum = 0.f;
        #pragma unroll
        for (int dy = 0; dy < 4; dy++) {
            float4 v = *(const float4*)(p + (py + dy) * 8 + pxq);
            sum += v.x + v.y + v.z + v.w;
        }
        scode[s] = sum * (1.f / 16.f);
    }
    __syncthreads();
    {   // logits: 32 outputs x 2 threads (k-halves), float4 loads
        int m = t & 31, half = t >> 5;
        const float4* c4 = (const float4*)(scode + half * 256);
        const float4* a4 = (const float4*)(aw + (size_t)(ch * 32 + m) * 512 + half * 256);
        float s = (half == 0) ? ab[ch * 32 + m] : 0.f;
        for (int k = 0; k < 64; k++) {
            float4 cv = c4[k], av = a4[k];
            s += cv.x * av.x + cv.y * av.y + cv.z * av.z + cv.w * av.w;
        }
        s += __shfl_down(s, 32, 64);
        if (half == 0) y[m] = s;
    }
    __syncthreads();
    if (t == 0) {
        float mx = y[0];
        for (int m = 1; m < 32; m++) mx = fmaxf(mx, y[m]);
        float e[32];
        float sum = 0.f;
        for (int m = 0; m < 32; m++) { e[m] = expf(y[m] - mx); sum += e[m]; }
        float inv = 1.f / sum;
        float cum = 0.f;
        float* vb = vert + (b * 3 + ch) * 33;
        float* ob = out_v + (b * 3 + ch) * 33;
        vb[0] = 0.f; ob[0] = 0.f; vsh[0] = 0.f;
        for (int m = 0; m < 32; m++) {
            cum += e[m] * inv;
            vb[m + 1] = cum; ob[m + 1] = cum; vsh[m + 1] = cum;
        }
    }
    __syncthreads();
    float* T = gT + (size_t)(b * 3 + ch) * 1280;
    for (int u = t; u < 256; u += 64) {
        float lo = (float)u * (1.f / 256.f);        // exact
        float hi = (float)(u + 1) * (1.f / 256.f);  // exact
        int n0 = 0, nin = 0;
        float vs = 2.0f;
        #pragma unroll
        for (int m = 0; m < 33; m++) {
            float vm = vsh[m];
            n0 += (vm <= lo) ? 1 : 0;
            if (vm > lo && vm < hi) { if (nin == 0) vs = vm; nin++; }
        }
        int i0 = n0 < 1 ? 1 : (n0 > 32 ? 32 : n0);
        int i1 = (n0 + 1) < 1 ? 1 : ((n0 + 1) > 32 ? 32 : (n0 + 1));
        float m0 = 1.f / (vsh[i0] - vsh[i0 - 1] + 1e-8f);
        float c0 = (float)(i0 - 1) - vsh[i0 - 1] * m0;
        float m1 = 1.f / (vsh[i1] - vsh[i1 - 1] + 1e-8f);
        float c1 = (float)(i1 - 1) - vsh[i1 - 1] * m1;
        if (nin >= 2) { vs = 2.0f; m0 = __int_as_float(0x7fc00000); c0 = 0.f; }
        T[u * 5]     = vs;
        T[u * 5 + 1] = m0;
        T[u * 5 + 2] = c0;
        T[u * 5 + 3] = m1;
        T[u * 5 + 4] = c1;
    }
}

// ---------------- fused LUT-gen + cell-gather: 48B record per (i0,j0,k0), 64B stride -------
// Directly evaluates Sum_r bw[..]*wt[r] for all 4 (i,j) corners x {k0,k0+1} x {r,g,b},
// packs 24 halves = 3 float4 words, corner-major (matches decode_lerp3 consumption order).
__global__ void k_cells(const float* __restrict__ bw, const float* __restrict__ wtp,
                        float4* __restrict__ cells) {
    int gid = blockIdx.x * 256 + threadIdx.x;     // 4*32768 = 131072
    if (gid >= BATCH * 32768) return;
    int b = gid >> 15;
    int cell = gid & 32767;
    int k0 = cell & 31, j0 = (cell >> 5) & 31, i0 = cell >> 10;
    float w0 = wtp[b * 3], w1 = wtp[b * 3 + 1], w2 = wtp[b * 3 + 2];
    int ci[4] = { (i0 * 33 + j0) * 33 + k0,
                  (i0 * 33 + j0 + 1) * 33 + k0,
                  ((i0 + 1) * 33 + j0) * 33 + k0,
                  ((i0 + 1) * 33 + j0 + 1) * 33 + k0 };
    float h[24];
    #pragma unroll
    for (int c = 0; c < 4; c++) {
        #pragma unroll
        for (int kk = 0; kk < 2; kk++) {
            int id2 = ci[c] + kk;
            #pragma unroll
            for (int pl = 0; pl < 3; pl++) {
                const float* p = bw + ((size_t)(pl * LUT_D3 + id2)) * 3;
                h[c * 6 + kk * 3 + pl] = p[0] * w0 + p[1] * w1 + p[2] * w2;
            }
        }
    }
    union { float4 f4[3]; __half hh[24]; } u;
    #pragma unroll
    for (int i = 0; i < 24; i++) u.hh[i] = __float2half_rn(h[i]);
    float4* dst = cells + (size_t)gid * 4;        // 4th slot never written/read
    dst[0] = u.f4[0]; dst[1] = u.f4[1]; dst[2] = u.f4[2];
}

// ---------------- per-pixel linear-table search (stride-5 LDS, bank-spread) ----------------
__device__ __forceinline__ void searchL5(const float* __restrict__ T,
                                         const float* __restrict__ v33,
                                         float x, int& i0, float& f) {
    int u = (int)(x * 256.f);                   // exact floor (x*2^8 lossless)
    u = u < 0 ? 0 : (u > 255 ? 255 : u);
    const float* e = T + u * 5;                 // stride 5: banks 5u%32 cover all 32
    float vs = e[0];
    float coord = (x < vs) ? fmaf(e[1], x, e[2]) : fmaf(e[3], x, e[4]);
    if (!(coord == coord)) {                    // NaN marker: exact fallback (~never)
        int lo = 0, hi = LUT_D;
        while (lo < hi) { int mid = (lo + hi) >> 1; if (v33[mid] <= x) lo = mid + 1; else hi = mid; }
        int idx = lo < 1 ? 1 : (lo > LUT_D - 1 ? LUT_D - 1 : lo);
        float vl = v33[idx - 1], vh = v33[idx];
        coord = (float)(idx - 1) + (x - vl) / (vh - vl + 1e-8f);
    }
    coord = fminf(fmaxf(coord, 0.f), (float)(LUT_D - 1));
    i0 = (int)coord;
    if (i0 > LUT_D - 2) i0 = LUT_D - 2;
    f = coord - (float)i0;
}

// decode one corner (3 packed fp16 words = r0,g0,b0,r1,g1,b1), lerp along blue
__device__ __forceinline__ void decode_lerp3(float wa, float wb, float wc, float fb,
                                             float& rv, float& gv, float& bv) {
    union { float f; __half2 h; } u0, u1, u2;
    u0.f = wa; u1.f = wb; u2.f = wc;
    float2 a = __half22float2(u0.h);   // r0, g0
    float2 b = __half22float2(u1.h);   // b0, r1
    float2 c = __half22float2(u2.h);   // g1, b1
    rv = fmaf(fb, b.y - a.x, a.x);
    gv = fmaf(fb, c.x - a.y, a.y);
    bv = fmaf(fb, c.y - b.x, b.x);
}

__global__ void __launch_bounds__(256) k_transform(const float* __restrict__ lq,
                                                   const float4* __restrict__ cells,
                                                   const float* __restrict__ vert,
                                                   const float* __restrict__ gT,
                                                   float* __restrict__ out) {
    // XCD-aware remap (dispatch round-robins blockIdx%8 across XCDs): 2 XCDs per image
    // -> each XCD's L2 holds exactly one image's 2MB cells table. Bijective for grid 4096.
    int orig = blockIdx.x;
    int xcd  = orig & 7;
    int bimg = xcd >> 1;
    int blk  = ((orig >> 3) << 1) | (xcd & 1);

    __shared__ float sT[3840];                    // 3 ch * 256 bins * 5
    __shared__ float sv[100];

    // issue pixel loads before the staging barrier (independent of LDS)
    int p0 = blk * 1024 + threadIdx.x * 4;        // 4 px per thread
    const float* lr = lq + (size_t)bimg * 3 * HW_IMG + p0;
    float4 r4 = *(const float4*)(lr);
    float4 g4 = *(const float4*)(lr + HW_IMG);
    float4 b4 = *(const float4*)(lr + 2 * HW_IMG);

    for (int i = threadIdx.x; i < 3840; i += 256) sT[i] = gT[bimg * 3840 + i];
    if (threadIdx.x < 99) sv[threadIdx.x] = vert[bimg * 99 + threadIdx.x];
    __syncthreads();

    float rr[4] = {r4.x, r4.y, r4.z, r4.w};
    float gg[4] = {g4.x, g4.y, g4.z, g4.w};
    float bb[4] = {b4.x, b4.y, b4.z, b4.w};

    // phase 1: all searches (flat, loop-free)
    int cidx[4];
    float fra[4], fga[4], fba[4];
    #pragma unroll
    for (int i = 0; i < 4; i++) {
        int i0, j0, k0;
        searchL5(sT,        sv,      rr[i], i0, fra[i]);
        searchL5(sT + 1280, sv + 33, gg[i], j0, fga[i]);
        searchL5(sT + 2560, sv + 66, bb[i], k0, fba[i]);
        cidx[i] = ((i0 * 32 + j0) << 5) + k0;
    }
    // phase 2: issue all cell loads (independent lines -> max MLP)
    float4 c0[4], c1[4], c2[4];
    #pragma unroll
    for (int i = 0; i < 4; i++) {
        const float4* p = cells + (((size_t)(bimg << 15) + cidx[i]) << 2);
        c0[i] = p[0]; c1[i] = p[1]; c2[i] = p[2];
    }
    // phase 3: decode + bilinear blend
    float ro[4], go[4], bo[4];
    #pragma unroll
    for (int i = 0; i < 4; i++) {
        float fb = fba[i];
        float r00, g00, b00, r01, g01, b01, r10, g10, b10, r11, g11, b11;
        decode_lerp3(c0[i].x, c0[i].y, c0[i].z, fb, r00, g00, b00);
        decode_lerp3(c0[i].w, c1[i].x, c1[i].y, fb, r01, g01, b01);
        decode_lerp3(c1[i].z, c1[i].w, c2[i].x, fb, r10, g10, b10);
        decode_lerp3(c2[i].y, c2[i].z, c2[i].w, fb, r11, g11, b11);
        float fr = fra[i], fg = fga[i];
        float w00 = (1.f - fr) * (1.f - fg), w01 = (1.f - fr) * fg;
        float w10 = fr * (1.f - fg),         w11 = fr * fg;
        float rx = r00 * w00 + r01 * w01 + r10 * w10 + r11 * w11;
        float ry = g00 * w00 + g01 * w01 + g10 * w10 + g11 * w11;
        float rz = b00 * w00 + b01 * w01 + b10 * w10 + b11 * w11;
        ro[i] = fminf(fmaxf(rx, 0.f), 1.f);
        go[i] = fminf(fmaxf(ry, 0.f), 1.f);
        bo[i] = fminf(fmaxf(rz, 0.f), 1.f);
    }
    float* op = out + (size_t)bimg * 3 * HW_IMG + p0;
    float4 o0 = {ro[0], ro[1], ro[2], ro[3]};
    float4 o1 = {go[0], go[1], go[2], go[3]};
    float4 o2 = {bo[0], bo[1], bo[2], bo[3]};
    *(float4*)(op) = o0;
    *(float4*)(op + HW_IMG) = o1;
    *(float4*)(op + 2 * HW_IMG) = o2;
}

extern "C" void kernel_launch(void* const* d_in, const int* in_sizes, int n_in,
                              void* d_out, int out_size, void* d_ws, size_t ws_size,
                              hipStream_t stream) {
    const float* lq  = (const float*)d_in[0];
    const float* w1  = (const float*)d_in[1];
    const float* b1  = (const float*)d_in[2];
    const float* g1  = (const float*)d_in[3];
    const float* be1 = (const float*)d_in[4];
    const float* w2  = (const float*)d_in[5];
    const float* b2  = (const float*)d_in[6];
    const float* g2  = (const float*)d_in[7];
    const float* be2 = (const float*)d_in[8];
    const float* w3  = (const float*)d_in[9];
    const float* b3  = (const float*)d_in[10];
    const float* g3  = (const float*)d_in[11];
    const float* be3 = (const float*)d_in[12];
    const float* w4  = (const float*)d_in[13];
    const float* b4  = (const float*)d_in[14];
    const float* g4  = (const float*)d_in[15];
    const float* be4 = (const float*)d_in[16];
    const float* w5  = (const float*)d_in[17];
    const float* b5  = (const float*)d_in[18];
    const float* lw  = (const float*)d_in[19];
    const float* lb  = (const float*)d_in[20];
    const float* bw  = (const float*)d_in[21];
    const float* aw  = (const float*)d_in[22];
    const float* ab  = (const float*)d_in[23];

    // Workspace: cells (2,097,152 floats) aliases f1..f5 (1,998,848 total) -- all feature
    // maps are dead before k_cells runs (f5 consumed by k_head). Tail region disjoint.
    float* ws    = (float*)d_ws;
    float* cells = ws;                     // 4*32768 cells * 16 floats = 2,097,152
    float* f1    = ws;                     // 1,048,576  [4,16,128,128]
    float* f2    = f1 + 1048576;           //   524,288  [4,32,64,64]
    float* f3    = f2 + 524288;            //   262,144  [4,64,32,32]
    float* f4    = f3 + 262144;            //   131,072  [4,128,16,16]
    float* f5    = f4 + 131072;            //    32,768  [4,128,8,8]  (ends 1,998,848)
    float* tail  = ws + 2097152;
    float* wt    = tail;                   // 12
    float* vert  = wt + 12;                // 396
    float* part1 = vert + 396;             // 4*16*256*2  = 32,768
    float* part2 = part1 + 32768;          // 4*32*64*2   = 16,384
    float* part3 = part2 + 16384;          // 4*64*16*2   =  8,192
    float* part4 = part3 + 8192;           // 4*128*4*2   =  4,096
    float* gT    = part4 + 4096;           // 12 * 256 * 5 = 15,360
                                           // end ~= 2,174,360 floats (8.7 MB)

    float* outs  = (float*)d_out;
    float* out_w = outs + (size_t)BATCH * 3 * HW_IMG;  // 12582912
    float* out_v = out_w + 12;

    // S1: lq (fused resize) -> f1 [4,16,128,128]; grid 4*16*16*1 = 1024
    k_conv2<3, 16, 128, 128, 3, false, true, true><<<1024, 256, 0, stream>>>(
        lq, nullptr, nullptr, nullptr, 0.f, 0, w1, b1, f1, part1);
    // S2: f1 -> f2 [4,32,64,64]; fused IN from part1; grid 4*8*8*2 = 512
    k_conv2<16, 32, 64, 64, 16, true, false, true><<<512, 256, 0, stream>>>(
        f1, part1, g1, be1, 1.f / 16384.f, 256, w2, b2, f2, part2);
    // S3: f2 -> f3 [4,64,32,32]; grid 4*4*4*4 = 256
    k_conv2<32, 64, 32, 32, 32, true, false, true><<<256, 256, 0, stream>>>(
        f2, part2, g2, be2, 1.f / 4096.f, 64, w3, b3, f3, part3);
    // S4: f3 -> f4 [4,128,16,16]; ic-chunked (2x32); grid 4*2*2*8 = 128
    k_conv2<64, 128, 16, 16, 32, true, false, true><<<128, 256, 0, stream>>>(
        f3, part3, g3, be3, 1.f / 1024.f, 16, w4, b4, f4, part4);
    // S5: f4 -> f5 [4,128,8,8]; ic-chunked (4x32); grid 4*1*1*8 = 32
    k_conv2<128, 128, 8, 8, 32, true, false, false><<<32, 256, 0, stream>>>(
        f4, part4, g4, be4, 1.f / 256.f, 4, w5, b5, f5, nullptr);
    // head: pool + weights + vertices + search table
    k_head<<<13, 64, 0, stream>>>(f5, lw, lb, aw, ab, wt, vert, gT, out_w, out_v);
    // fused lutgen+cellgen
    k_cells<<<512, 256, 0, stream>>>(bw, wt, (float4*)cells);
    // transform
    k_transform<<<BATCH * 1024, 256, 0, stream>>>(lq, (const float4*)cells, vert, gT, outs);
}

// Round 6
// 289.263 us; speedup vs baseline: 1.1298x; 1.1298x over previous
//
#include <hip/hip_runtime.h>
#include <hip/hip_fp16.h>
#include <math.h>

#define LUT_D 33
#define LUT_D3 35937   // 33^3
#define NEG 0.2f
#define BATCH 4
#define HW_IMG 1048576 // 1024*1024

// ---------------- fused conv3x3 s2 p1 (+LeakyReLU if NSPLIT==1), fused IN, fused resize ----
// block = (b, ty, tx, icc_i, ocg); 256 threads = 64 px * 4 oc-lanes (4 oc each).
// NSPLIT>1: block computes partial over its 16-ic slice -> raw partials (k_combine finishes).
// NORM_IN: per-block recompute of (sc,sh) InstanceNorm pairs from producer's part stats
//          (redundant across blocks; kills the k_norm launch).
// RESIZE_IN: input = lq 1024x1024; staged pixels = 4->1 bilinear tap
//            0.25*(lq[4y+1,4x+1..2]+lq[4y+2,4x+1..2]) via 16B-aligned float4 at col 4x.
// STATS_OUT (NSPLIT==1): per-(oc,tile) wave partial sums of activated outputs.
template<int IC, int OC, int OH, int OW, int NSPLIT, bool NORM_IN, bool RESIZE_IN, bool STATS_OUT>
__global__ void __launch_bounds__(256) k_conv2(
    const float* __restrict__ in, const float* __restrict__ part_in,
    const float* __restrict__ g, const float* __restrict__ be, float invN, int ntin,
    const float* __restrict__ w, const float* __restrict__ bias,
    float* __restrict__ out, float* __restrict__ part_out) {
    constexpr int IH = OH * 2, IW = OW * 2;
    constexpr int ICB = IC / NSPLIT;              // <= 32
    constexpr int TROW = 20, TSZ = 17 * TROW;     // 340 floats per ic tile
    constexpr int NTX = OW / 8, NTY = OH / 8, NOCG = OC / 16;
    constexpr int NT = NTX * NTY;
    constexpr int PX = OH * OW;

    __shared__ float sIn[ICB * TSZ];
    __shared__ float swl[16 * ICB * 9];
    __shared__ float sNm[NORM_IN ? IC * 2 : 1];

    int id = blockIdx.x;
    int ocg   = id % NOCG;   id /= NOCG;
    int icc_i = id % NSPLIT; id /= NSPLIT;
    int tx    = id % NTX;    id /= NTX;
    int ty    = id % NTY;    id /= NTY;
    int b     = id;
    int icc   = icc_i * ICB;

    int t    = threadIdx.x;
    int lane = t >> 6;          // 0..3
    int px   = t & 63;
    int py   = px >> 3, pxx = px & 7;
    int oc0  = ocg * 16 + lane * 4;

    // ---- fused InstanceNorm pair computation (all IC channels; block uses its slice) ----
    if (NORM_IN) {
        constexpr int P = 256 / IC;             // threads per channel (2..16)
        int c = t / P, r = t % P;
        float s1 = 0.f, s2 = 0.f;
        for (int i = r; i < ntin; i += P) {
            const float* pp = part_in + ((size_t)(b * IC + c) * ntin + i) * 2;
            s1 += pp[0]; s2 += pp[1];
        }
        #pragma unroll
        for (int off = P >> 1; off > 0; off >>= 1) {
            s1 += __shfl_down(s1, off, 64);
            s2 += __shfl_down(s2, off, 64);
        }
        if (r == 0) {
            float m   = s1 * invN;
            float var = s2 * invN - m * m;
            float sc  = g[c] * rsqrtf(var + 1e-5f);
            sNm[c * 2]     = sc;
            sNm[c * 2 + 1] = be[c] - m * sc;
        }
    }

    // ---- stage weights for this ic-slice ----
    if (IC == ICB) {
        const float4* wsrc = (const float4*)(w + (size_t)ocg * 16 * IC * 9);
        for (int i = t; i < 16 * IC * 9 / 4; i += 256) ((float4*)swl)[i] = wsrc[i];
    } else {
        constexpr int WQ = ICB * 9 / 4;
        for (int i = t; i < 16 * WQ; i += 256) {
            int ol = i / WQ, qi = i % WQ;
            ((float4*)swl)[ol * WQ + qi] =
                *(const float4*)(w + ((size_t)(ocg * 16 + ol) * IC + icc) * 9 + qi * 4);
        }
    }
    if (NORM_IN) __syncthreads();               // sNm ready before staging uses it

    // ---- stage input tile: 4 float4 + 1 halo scalar per (ic,row) ----
    int iy0 = ty * 16 - 1;
    int xbase = tx * 16;
    if (RESIZE_IN) {
        for (int q = t; q < ICB * 17 * 4; q += 256) {
            int ic_l = q / 68;
            int r2   = q % 68;
            int row  = r2 >> 2, quad = r2 & 3;
            int iy = iy0 + row;
            float4 v = {0.f, 0.f, 0.f, 0.f};
            if (iy >= 0 && iy < IH) {
                const float* lb_ = in + (size_t)(b * IC + icc + ic_l) * HW_IMG
                                      + (size_t)(4 * iy + 1) * 1024;
                int c0 = (xbase + quad * 4) * 4;          // 16B-aligned
                const float4* pa = (const float4*)(lb_ + c0);
                const float4* pb = (const float4*)(lb_ + 1024 + c0);
                float4 a0 = pa[0], a1 = pa[1], a2 = pa[2], a3 = pa[3];
                float4 q0 = pb[0], q1 = pb[1], q2 = pb[2], q3 = pb[3];
                v.x = 0.25f * (a0.y + a0.z + q0.y + q0.z);
                v.y = 0.25f * (a1.y + a1.z + q1.y + q1.z);
                v.z = 0.25f * (a2.y + a2.z + q2.y + q2.z);
                v.w = 0.25f * (a3.y + a3.z + q3.y + q3.z);
            }
            *(float4*)(sIn + ic_l * TSZ + row * TROW + 4 + quad * 4) = v;
        }
        for (int h = t; h < ICB * 17; h += 256) {
            int ic_l = h / 17, row = h % 17;
            int iy = iy0 + row, ix = xbase - 1;
            float v = 0.f;
            if (iy >= 0 && iy < IH && ix >= 0) {
                const float* lb_ = in + (size_t)(b * IC + icc + ic_l) * HW_IMG
                                      + (size_t)(4 * iy + 1) * 1024;
                float4 a = *(const float4*)(lb_ + ix * 4);
                float4 q0 = *(const float4*)(lb_ + 1024 + ix * 4);
                v = 0.25f * (a.y + a.z + q0.y + q0.z);
            }
            sIn[ic_l * TSZ + row * TROW + 3] = v;
        }
    } else {
        const float* inb = in + (size_t)(b * IC + icc) * (IH * IW);
        for (int q = t; q < ICB * 17 * 4; q += 256) {
            int ic_l = q / 68;
            int r2   = q % 68;
            int row  = r2 >> 2, quad = r2 & 3;
            int iy = iy0 + row;
            float4 v = {0.f, 0.f, 0.f, 0.f};
            if (iy >= 0 && iy < IH) {
                v = *(const float4*)(inb + (size_t)ic_l * (IH * IW)
                                         + (size_t)iy * IW + xbase + quad * 4);
                if (NORM_IN) {
                    float sc = sNm[(icc + ic_l) * 2], sh = sNm[(icc + ic_l) * 2 + 1];
                    v.x = v.x * sc + sh; v.y = v.y * sc + sh;
                    v.z = v.z * sc + sh; v.w = v.w * sc + sh;
                }
            }
            *(float4*)(sIn + ic_l * TSZ + row * TROW + 4 + quad * 4) = v;
        }
        for (int h = t; h < ICB * 17; h += 256) {
            int ic_l = h / 17, row = h % 17;
            int iy = iy0 + row, ix = xbase - 1;
            float v = 0.f;
            if (iy >= 0 && iy < IH && ix >= 0) {
                v = inb[(size_t)ic_l * (IH * IW) + (size_t)iy * IW + ix];
                if (NORM_IN) v = v * sNm[(icc + ic_l) * 2] + sNm[(icc + ic_l) * 2 + 1];
            }
            sIn[ic_l * TSZ + row * TROW + 3] = v;
        }
    }
    __syncthreads();

    // ---- compute ----
    float acc[4];
    #pragma unroll
    for (int j = 0; j < 4; j++) acc[j] = (NSPLIT == 1) ? bias[oc0 + j] : 0.f;

    for (int i2 = 0; i2 < ICB; i2++) {
        const float* tp = sIn + i2 * TSZ + py * 2 * TROW + pxx * 2 + 3;
        float x0 = tp[0],        x1 = tp[1],        x2 = tp[2];
        float x3 = tp[TROW],     x4 = tp[TROW + 1], x5 = tp[TROW + 2];
        float x6 = tp[2 * TROW], x7 = tp[2 * TROW + 1], x8 = tp[2 * TROW + 2];
        #pragma unroll
        for (int j = 0; j < 4; j++) {
            const float* wp = swl + ((lane * 4 + j) * ICB + i2) * 9;
            acc[j] = fmaf(x0, wp[0], acc[j]);
            acc[j] = fmaf(x1, wp[1], acc[j]);
            acc[j] = fmaf(x2, wp[2], acc[j]);
            acc[j] = fmaf(x3, wp[3], acc[j]);
            acc[j] = fmaf(x4, wp[4], acc[j]);
            acc[j] = fmaf(x5, wp[5], acc[j]);
            acc[j] = fmaf(x6, wp[6], acc[j]);
            acc[j] = fmaf(x7, wp[7], acc[j]);
            acc[j] = fmaf(x8, wp[8], acc[j]);
        }
    }

    int oy = ty * 8 + py, ox = tx * 8 + pxx;
    if (NSPLIT == 1) {
        int tile = ty * NTX + tx;
        #pragma unroll
        for (int j = 0; j < 4; j++) {
            float a = acc[j];
            a = a >= 0.f ? a : NEG * a;
            out[((size_t)(b * OC + oc0 + j) * OH + oy) * OW + ox] = a;
            if (STATS_OUT) {
                float s1 = a, s2 = a * a;
                for (int off = 32; off > 0; off >>= 1) {
                    s1 += __shfl_down(s1, off, 64);
                    s2 += __shfl_down(s2, off, 64);
                }
                if (px == 0) {
                    size_t pi = ((size_t)(b * OC + oc0 + j) * NT + tile) * 2;
                    part_out[pi] = s1; part_out[pi + 1] = s2;
                }
            }
        }
    } else {
        #pragma unroll
        for (int j = 0; j < 4; j++) {
            part_out[(size_t)icc_i * (BATCH * OC * PX) +
                     (size_t)(b * OC + oc0 + j) * PX + oy * OW + ox] = acc[j];
        }
    }
}

// ---------------- combine ic-split partials: + bias, LeakyReLU, optional stats -------------
template<int NSPLIT, int OC, int PX, bool STATS>
__global__ void k_combine(const float* __restrict__ ps, const float* __restrict__ bias,
                          float* __restrict__ out, float* __restrict__ spart) {
    constexpr int TOT = BATCH * OC * PX;
    int e = blockIdx.x * 256 + threadIdx.x;
    if (e >= TOT) return;
    float s = 0.f;
    #pragma unroll
    for (int k = 0; k < NSPLIT; k++) s += ps[(size_t)k * TOT + e];
    int oc = (e / PX) % OC;
    s += bias[oc];
    s = s >= 0.f ? s : NEG * s;
    out[e] = s;
    if (STATS) {
        float s1 = s, s2 = s * s;
        for (int off = 32; off > 0; off >>= 1) {
            s1 += __shfl_down(s1, off, 64);
            s2 += __shfl_down(s2, off, 64);
        }
        if ((threadIdx.x & 63) == 0) {
            int widx = e >> 6;
            spart[widx * 2] = s1; spart[widx * 2 + 1] = s2;
        }
    }
}

// ---------------- head: pool(f5) -> codes; weights; vertices; 5-float search table --------
// Table per (b,ch), 256 bins u (x*2^8 exact): entry {vs, m0, c0, m1, c1} at stride 5:
//   coord = (x < vs) ? m0*x+c0 : m1*x+c1   (exact when <=1 interior vertex per bin;
//   >=2 interior -> m0=NaN marker -> transform binary-search fallback).
__global__ void k_head(const float* __restrict__ f5, const float* __restrict__ lw,
                       const float* __restrict__ lb, const float* __restrict__ aw,
                       const float* __restrict__ ab, float* __restrict__ wt,
                       float* __restrict__ vert, float* __restrict__ gT,
                       float* __restrict__ out_w, float* __restrict__ out_v) {
    int blk = blockIdx.x;
    int t = threadIdx.x;  // 64 threads
    if (blk == 12) {
        __shared__ float sc2[2048];
        for (int s = t; s < 2048; s += 64) {
            int b = s >> 9, rest = s & 511, oc = rest >> 2, q = rest & 3;
            int py = (q >> 1) * 4, pxq = (q & 1) * 4;
            const float* p = f5 + (size_t)(b * 128 + oc) * 64;
            float sum = 0.f;
            #pragma unroll
            for (int dy = 0; dy < 4; dy++) {
                float4 v = *(const float4*)(p + (py + dy) * 8 + pxq);
                sum += v.x + v.y + v.z + v.w;
            }
            sc2[s] = sum * (1.f / 16.f);
        }
        __syncthreads();
        if (t < 48) {
            int j = t >> 2, q = t & 3;          // 12 outputs x 4 threads
            int b = j / 3, jj = j % 3;
            const float4* c4 = (const float4*)(sc2 + b * 512 + q * 128);
            const float4* l4 = (const float4*)(lw + jj * 512 + q * 128);
            float s = 0.f;
            for (int k = 0; k < 32; k++) {
                float4 cv = c4[k], lv = l4[k];
                s += cv.x * lv.x + cv.y * lv.y + cv.z * lv.z + cv.w * lv.w;
            }
            s += __shfl_down(s, 2, 64);
            s += __shfl_down(s, 1, 64);
            if (q == 0) { s += lb[jj]; wt[j] = s; out_w[j] = s; }
        }
        return;
    }
    int b = blk / 3, ch = blk % 3;
    __shared__ float scode[512];
    __shared__ float y[32];
    __shared__ float vsh[33];
    for (int s = t; s < 512; s += 64) {
        int oc = s >> 2, q = s & 3;
        int py = (q >> 1) * 4, pxq = (q & 1) * 4;
        const float* p = f5 + (size_t)(b * 128 + oc) * 64;
        float sum = 0.f;
        #pragma unroll
        for (int dy = 0; dy < 4; dy++) {
            float4 v = *(const float4*)(p + (py + dy) * 8 + pxq);
            sum += v.x + v.y + v.z + v.w;
        }
        scode[s] = sum * (1.f / 16.f);
    }
    __syncthreads();
    {   // logits: 32 outputs x 2 threads (k-halves), float4 loads
        int m = t & 31, half = t >> 5;
        const float4* c4 = (const float4*)(scode + half * 256);
        const float4* a4 = (const float4*)(aw + (size_t)(ch * 32 + m) * 512 + half * 256);
        float s = (half == 0) ? ab[ch * 32 + m] : 0.f;
        for (int k = 0; k < 64; k++) {
            float4 cv = c4[k], av = a4[k];
            s += cv.x * av.x + cv.y * av.y + cv.z * av.z + cv.w * av.w;
        }
        s += __shfl_down(s, 32, 64);
        if (half == 0) y[m] = s;
    }
    __syncthreads();
    if (t == 0) {
        float mx = y[0];
        for (int m = 1; m < 32; m++) mx = fmaxf(mx, y[m]);
        float e[32];
        float sum = 0.f;
        for (int m = 0; m < 32; m++) { e[m] = expf(y[m] - mx); sum += e[m]; }
        float inv = 1.f / sum;
        float cum = 0.f;
        float* vb = vert + (b * 3 + ch) * 33;
        float* ob = out_v + (b * 3 + ch) * 33;
        vb[0] = 0.f; ob[0] = 0.f; vsh[0] = 0.f;
        for (int m = 0; m < 32; m++) {
            cum += e[m] * inv;
            vb[m + 1] = cum; ob[m + 1] = cum; vsh[m + 1] = cum;
        }
    }
    __syncthreads();
    float* T = gT + (size_t)(b * 3 + ch) * 1280;
    for (int u = t; u < 256; u += 64) {
        float lo = (float)u * (1.f / 256.f);        // exact
        float hi = (float)(u + 1) * (1.f / 256.f);  // exact
        int n0 = 0, nin = 0;
        float vs = 2.0f;
        #pragma unroll
        for (int m = 0; m < 33; m++) {
            float vm = vsh[m];
            n0 += (vm <= lo) ? 1 : 0;
            if (vm > lo && vm < hi) { if (nin == 0) vs = vm; nin++; }
        }
        int i0 = n0 < 1 ? 1 : (n0 > 32 ? 32 : n0);
        int i1 = (n0 + 1) < 1 ? 1 : ((n0 + 1) > 32 ? 32 : (n0 + 1));
        float m0 = 1.f / (vsh[i0] - vsh[i0 - 1] + 1e-8f);
        float c0 = (float)(i0 - 1) - vsh[i0 - 1] * m0;
        float m1 = 1.f / (vsh[i1] - vsh[i1 - 1] + 1e-8f);
        float c1 = (float)(i1 - 1) - vsh[i1 - 1] * m1;
        if (nin >= 2) { vs = 2.0f; m0 = __int_as_float(0x7fc00000); c0 = 0.f; }
        T[u * 5]     = vs;
        T[u * 5 + 1] = m0;
        T[u * 5 + 2] = c0;
        T[u * 5 + 3] = m1;
        T[u * 5 + 4] = c1;
    }
}

// ---------------- fused LUT-gen + cell-gather: 48B record per (i0,j0,k0), 64B stride -------
__global__ void k_cells(const float* __restrict__ bw, const float* __restrict__ wtp,
                        float4* __restrict__ cells) {
    int gid = blockIdx.x * 256 + threadIdx.x;     // 4*32768 = 131072
    if (gid >= BATCH * 32768) return;
    int b = gid >> 15;
    int cell = gid & 32767;
    int k0 = cell & 31, j0 = (cell >> 5) & 31, i0 = cell >> 10;
    float w0 = wtp[b * 3], w1 = wtp[b * 3 + 1], w2 = wtp[b * 3 + 2];
    int ci[4] = { (i0 * 33 + j0) * 33 + k0,
                  (i0 * 33 + j0 + 1) * 33 + k0,
                  ((i0 + 1) * 33 + j0) * 33 + k0,
                  ((i0 + 1) * 33 + j0 + 1) * 33 + k0 };
    float h[24];
    #pragma unroll
    for (int c = 0; c < 4; c++) {
        #pragma unroll
        for (int kk = 0; kk < 2; kk++) {
            int id2 = ci[c] + kk;
            #pragma unroll
            for (int pl = 0; pl < 3; pl++) {
                const float* p = bw + ((size_t)(pl * LUT_D3 + id2)) * 3;
                h[c * 6 + kk * 3 + pl] = p[0] * w0 + p[1] * w1 + p[2] * w2;
            }
        }
    }
    union { float4 f4[3]; __half hh[24]; } u;
    #pragma unroll
    for (int i = 0; i < 24; i++) u.hh[i] = __float2half_rn(h[i]);
    float4* dst = cells + (size_t)gid * 4;        // 4th slot never written/read
    dst[0] = u.f4[0]; dst[1] = u.f4[1]; dst[2] = u.f4[2];
}

// ---------------- per-pixel linear-table search (stride-5 LDS, bank-spread) ----------------
__device__ __forceinline__ void searchL5(const float* __restrict__ T,
                                         const float* __restrict__ v33,
                                         float x, int& i0, float& f) {
    int u = (int)(x * 256.f);                   // exact floor (x*2^8 lossless)
    u = u < 0 ? 0 : (u > 255 ? 255 : u);
    const float* e = T + u * 5;                 // stride 5: banks 5u%32 cover all 32
    float vs = e[0];
    float coord = (x < vs) ? fmaf(e[1], x, e[2]) : fmaf(e[3], x, e[4]);
    if (!(coord == coord)) {                    // NaN marker: exact fallback (~never)
        int lo = 0, hi = LUT_D;
        while (lo < hi) { int mid = (lo + hi) >> 1; if (v33[mid] <= x) lo = mid + 1; else hi = mid; }
        int idx = lo < 1 ? 1 : (lo > LUT_D - 1 ? LUT_D - 1 : lo);
        float vl = v33[idx - 1], vh = v33[idx];
        coord = (float)(idx - 1) + (x - vl) / (vh - vl + 1e-8f);
    }
    coord = fminf(fmaxf(coord, 0.f), (float)(LUT_D - 1));
    i0 = (int)coord;
    if (i0 > LUT_D - 2) i0 = LUT_D - 2;
    f = coord - (float)i0;
}

// decode one corner (3 packed fp16 words = r0,g0,b0,r1,g1,b1), lerp along blue
__device__ __forceinline__ void decode_lerp3(float wa, float wb, float wc, float fb,
                                             float& rv, float& gv, float& bv) {
    union { float f; __half2 h; } u0, u1, u2;
    u0.f = wa; u1.f = wb; u2.f = wc;
    float2 a = __half22float2(u0.h);   // r0, g0
    float2 b = __half22float2(u1.h);   // b0, r1
    float2 c = __half22float2(u2.h);   // g1, b1
    rv = fmaf(fb, b.y - a.x, a.x);
    gv = fmaf(fb, c.x - a.y, a.y);
    bv = fmaf(fb, c.y - b.x, b.x);
}

__global__ void __launch_bounds__(256) k_transform(const float* __restrict__ lq,
                                                   const float4* __restrict__ cells,
                                                   const float* __restrict__ vert,
                                                   const float* __restrict__ gT,
                                                   float* __restrict__ out) {
    // XCD-aware remap: 2 XCDs per image -> each XCD's L2 holds one image's 2MB cells.
    // Bijective for grid 2048 (8 px/thread).
    int orig = blockIdx.x;
    int xcd  = orig & 7;
    int bimg = xcd >> 1;
    int blk  = ((orig >> 3) << 1) | (xcd & 1);    // [0,512)

    __shared__ float sT[3840];                    // 3 ch * 256 bins * 5
    __shared__ float sv[100];

    // issue pixel loads before the staging barrier (independent of LDS)
    int p0 = blk * 2048 + threadIdx.x * 8;        // 8 px per thread
    const float* lr = lq + (size_t)bimg * 3 * HW_IMG + p0;
    float4 ra = *(const float4*)(lr);
    float4 rb = *(const float4*)(lr + 4);
    float4 ga = *(const float4*)(lr + HW_IMG);
    float4 gb = *(const float4*)(lr + HW_IMG + 4);
    float4 ba = *(const float4*)(lr + 2 * HW_IMG);
    float4 bb4 = *(const float4*)(lr + 2 * HW_IMG + 4);

    for (int i = threadIdx.x; i < 3840; i += 256) sT[i] = gT[bimg * 3840 + i];
    if (threadIdx.x < 99) sv[threadIdx.x] = vert[bimg * 99 + threadIdx.x];
    __syncthreads();

    float rr[8] = {ra.x, ra.y, ra.z, ra.w, rb.x, rb.y, rb.z, rb.w};
    float gg[8] = {ga.x, ga.y, ga.z, ga.w, gb.x, gb.y, gb.z, gb.w};
    float bb[8] = {ba.x, ba.y, ba.z, ba.w, bb4.x, bb4.y, bb4.z, bb4.w};

    // phase 1: 24 independent flat searches
    int cidx[8];
    float fra[8], fga[8], fba[8];
    #pragma unroll
    for (int i = 0; i < 8; i++) {
        int i0, j0, k0;
        searchL5(sT,        sv,      rr[i], i0, fra[i]);
        searchL5(sT + 1280, sv + 33, gg[i], j0, fga[i]);
        searchL5(sT + 2560, sv + 66, bb[i], k0, fba[i]);
        cidx[i] = ((i0 * 32 + j0) << 5) + k0;
    }
    // phase 2: issue all 8 cell-line loads (independent -> max MLP)
    float4 c0[8], c1[8], c2[8];
    #pragma unroll
    for (int i = 0; i < 8; i++) {
        const float4* p = cells + (((size_t)(bimg << 15) + cidx[i]) << 2);
        c0[i] = p[0]; c1[i] = p[1]; c2[i] = p[2];
    }
    // phase 3: decode + bilinear blend
    float ro[8], go[8], bo[8];
    #pragma unroll
    for (int i = 0; i < 8; i++) {
        float fb = fba[i];
        float r00, g00, b00, r01, g01, b01, r10, g10, b10, r11, g11, b11;
        decode_lerp3(c0[i].x, c0[i].y, c0[i].z, fb, r00, g00, b00);
        decode_lerp3(c0[i].w, c1[i].x, c1[i].y, fb, r01, g01, b01);
        decode_lerp3(c1[i].z, c1[i].w, c2[i].x, fb, r10, g10, b10);
        decode_lerp3(c2[i].y, c2[i].z, c2[i].w, fb, r11, g11, b11);
        float fr = fra[i], fg = fga[i];
        float w00 = (1.f - fr) * (1.f - fg), w01 = (1.f - fr) * fg;
        float w10 = fr * (1.f - fg),         w11 = fr * fg;
        float rx = r00 * w00 + r01 * w01 + r10 * w10 + r11 * w11;
        float ry = g00 * w00 + g01 * w01 + g10 * w10 + g11 * w11;
        float rz = b00 * w00 + b01 * w01 + b10 * w10 + b11 * w11;
        ro[i] = fminf(fmaxf(rx, 0.f), 1.f);
        go[i] = fminf(fmaxf(ry, 0.f), 1.f);
        bo[i] = fminf(fmaxf(rz, 0.f), 1.f);
    }
    float* op = out + (size_t)bimg * 3 * HW_IMG + p0;
    *(float4*)(op)                  = make_float4(ro[0], ro[1], ro[2], ro[3]);
    *(float4*)(op + 4)              = make_float4(ro[4], ro[5], ro[6], ro[7]);
    *(float4*)(op + HW_IMG)         = make_float4(go[0], go[1], go[2], go[3]);
    *(float4*)(op + HW_IMG + 4)     = make_float4(go[4], go[5], go[6], go[7]);
    *(float4*)(op + 2 * HW_IMG)     = make_float4(bo[0], bo[1], bo[2], bo[3]);
    *(float4*)(op + 2 * HW_IMG + 4) = make_float4(bo[4], bo[5], bo[6], bo[7]);
}

extern "C" void kernel_launch(void* const* d_in, const int* in_sizes, int n_in,
                              void* d_out, int out_size, void* d_ws, size_t ws_size,
                              hipStream_t stream) {
    const float* lq  = (const float*)d_in[0];
    const float* w1  = (const float*)d_in[1];
    const float* b1  = (const float*)d_in[2];
    const float* g1  = (const float*)d_in[3];
    const float* be1 = (const float*)d_in[4];
    const float* w2  = (const float*)d_in[5];
    const float* b2  = (const float*)d_in[6];
    const float* g2  = (const float*)d_in[7];
    const float* be2 = (const float*)d_in[8];
    const float* w3  = (const float*)d_in[9];
    const float* b3  = (const float*)d_in[10];
    const float* g3  = (const float*)d_in[11];
    const float* be3 = (const float*)d_in[12];
    const float* w4  = (const float*)d_in[13];
    const float* b4  = (const float*)d_in[14];
    const float* g4  = (const float*)d_in[15];
    const float* be4 = (const float*)d_in[16];
    const float* w5  = (const float*)d_in[17];
    const float* b5  = (const float*)d_in[18];
    const float* lw  = (const float*)d_in[19];
    const float* lb  = (const float*)d_in[20];
    const float* bw  = (const float*)d_in[21];
    const float* aw  = (const float*)d_in[22];
    const float* ab  = (const float*)d_in[23];

    // Workspace: cells (2,097,152 floats) aliases f1..f5 (dead before k_cells).
    // psplit4/5 alias f1 (dead after S2). Tail region disjoint.
    float* ws    = (float*)d_ws;
    float* cells = ws;                     // 4*32768 cells * 16 floats = 2,097,152
    float* f1    = ws;                     // 1,048,576  [4,16,128,128]
    float* f2    = f1 + 1048576;           //   524,288  [4,32,64,64]
    float* f3    = f2 + 524288;            //   262,144  [4,64,32,32]
    float* f4    = f3 + 262144;            //   131,072  [4,128,16,16]
    float* f5    = f4 + 131072;            //    32,768  [4,128,8,8]  (ends 1,998,848)
    float* psplit4 = f1;                   // 4*131072 = 524,288 (alias; f1 dead by S4)
    float* psplit5 = f1 + 524288;          // 8*32768  = 262,144
    float* tail  = ws + 2097152;
    float* wt    = tail;                   // 12
    float* vert  = wt + 12;                // 396
    float* part1 = vert + 396;             // 4*16*256*2  = 32,768
    float* part2 = part1 + 32768;          // 4*32*64*2   = 16,384
    float* part3 = part2 + 16384;          // 4*64*16*2   =  8,192
    float* part4 = part3 + 8192;           // 4*128*4*2   =  4,096
    float* gT    = part4 + 4096;           // 12 * 256 * 5 = 15,360

    float* outs  = (float*)d_out;
    float* out_w = outs + (size_t)BATCH * 3 * HW_IMG;  // 12582912
    float* out_v = out_w + 12;

    // S1: lq (fused resize) -> f1 [4,16,128,128]; grid 4*16*16*1 = 1024
    k_conv2<3, 16, 128, 128, 1, false, true, true><<<1024, 256, 0, stream>>>(
        lq, nullptr, nullptr, nullptr, 0.f, 0, w1, b1, f1, part1);
    // S2: f1 -> f2 [4,32,64,64]; fused IN from part1; grid 4*8*8*2 = 512
    k_conv2<16, 32, 64, 64, 1, true, false, true><<<512, 256, 0, stream>>>(
        f1, part1, g1, be1, 1.f / 16384.f, 256, w2, b2, f2, part2);
    // S3: f2 -> f3 [4,64,32,32]; fused IN from part2; grid 4*4*4*4 = 256
    k_conv2<32, 64, 32, 32, 1, true, false, true><<<256, 256, 0, stream>>>(
        f2, part2, g2, be2, 1.f / 4096.f, 64, w3, b3, f3, part3);
    // S4: f3 -> psplit4 (ic-split x4); grid 4*2*2*4*8 = 512; combine -> f4 + stats
    k_conv2<64, 128, 16, 16, 4, true, false, false><<<512, 256, 0, stream>>>(
        f3, part3, g3, be3, 1.f / 1024.f, 16, w4, b4, nullptr, psplit4);
    k_combine<4, 128, 256, true><<<512, 256, 0, stream>>>(psplit4, b4, f4, part4);
    // S5: f4 -> psplit5 (ic-split x8); grid 4*1*1*8*8 = 256; combine -> f5
    k_conv2<128, 128, 8, 8, 8, true, false, false><<<256, 256, 0, stream>>>(
        f4, part4, g4, be4, 1.f / 256.f, 4, w5, b5, nullptr, psplit5);
    k_combine<8, 128, 64, false><<<128, 256, 0, stream>>>(psplit5, b5, f5, nullptr);
    // head: pool + weights + vertices + search table
    k_head<<<13, 64, 0, stream>>>(f5, lw, lb, aw, ab, wt, vert, gT, out_w, out_v);
    // fused lutgen+cellgen
    k_cells<<<512, 256, 0, stream>>>(bw, wt, (float4*)cells);
    // transform: 8 px/thread, grid 2048
    k_transform<<<2048, 256, 0, stream>>>(lq, (const float4*)cells, vert, gT, outs);
}

// Round 7
// 279.649 us; speedup vs baseline: 1.1687x; 1.0344x over previous
//
#include <hip/hip_runtime.h>
#include <hip/hip_fp16.h>
#include <math.h>

#define LUT_D 33
#define LUT_D3 35937   // 33^3
#define NEG 0.2f
#define BATCH 4
#define HW_IMG 1048576 // 1024*1024

// ---------------- fused conv3x3 s2 p1 (+LeakyReLU if NSPLIT==1), fused IN, fused resize ----
// block = (b, ty, tx, icc_i, ocg); 256 threads = 64 px * 4 oc-lanes (4 oc each).
// NSPLIT>1: block computes partial over its ic slice -> raw partials (k_combine finishes).
// NORM_IN: per-block recompute of (sc,sh) InstanceNorm pairs from producer's part stats.
// RESIZE_IN: input = lq 1024x1024; staged pixels = 4->1 bilinear tap.
// STATS_OUT (NSPLIT==1): per-(oc,tile) wave partial sums of activated outputs.
template<int IC, int OC, int OH, int OW, int NSPLIT, bool NORM_IN, bool RESIZE_IN, bool STATS_OUT>
__global__ void __launch_bounds__(256) k_conv2(
    const float* __restrict__ in, const float* __restrict__ part_in,
    const float* __restrict__ g, const float* __restrict__ be, float invN, int ntin,
    const float* __restrict__ w, const float* __restrict__ bias,
    float* __restrict__ out, float* __restrict__ part_out) {
    constexpr int IH = OH * 2, IW = OW * 2;
    constexpr int ICB = IC / NSPLIT;              // <= 32
    constexpr int TROW = 20, TSZ = 17 * TROW;     // 340 floats per ic tile
    constexpr int NTX = OW / 8, NTY = OH / 8, NOCG = OC / 16;
    constexpr int NT = NTX * NTY;
    constexpr int PX = OH * OW;

    __shared__ float sIn[ICB * TSZ];
    __shared__ float swl[16 * ICB * 9];
    __shared__ float sNm[NORM_IN ? IC * 2 : 1];

    int id = blockIdx.x;
    int ocg   = id % NOCG;   id /= NOCG;
    int icc_i = id % NSPLIT; id /= NSPLIT;
    int tx    = id % NTX;    id /= NTX;
    int ty    = id % NTY;    id /= NTY;
    int b     = id;
    int icc   = icc_i * ICB;

    int t    = threadIdx.x;
    int lane = t >> 6;          // 0..3
    int px   = t & 63;
    int py   = px >> 3, pxx = px & 7;
    int oc0  = ocg * 16 + lane * 4;

    // ---- fused InstanceNorm pair computation ----
    if (NORM_IN) {
        constexpr int P = 256 / IC;             // threads per channel (2..16)
        int c = t / P, r = t % P;
        float s1 = 0.f, s2 = 0.f;
        for (int i = r; i < ntin; i += P) {
            const float* pp = part_in + ((size_t)(b * IC + c) * ntin + i) * 2;
            s1 += pp[0]; s2 += pp[1];
        }
        #pragma unroll
        for (int off = P >> 1; off > 0; off >>= 1) {
            s1 += __shfl_down(s1, off, 64);
            s2 += __shfl_down(s2, off, 64);
        }
        if (r == 0) {
            float m   = s1 * invN;
            float var = s2 * invN - m * m;
            float sc  = g[c] * rsqrtf(var + 1e-5f);
            sNm[c * 2]     = sc;
            sNm[c * 2 + 1] = be[c] - m * sc;
        }
    }

    // ---- stage weights for this ic-slice ----
    if (IC == ICB) {
        const float4* wsrc = (const float4*)(w + (size_t)ocg * 16 * IC * 9);
        for (int i = t; i < 16 * IC * 9 / 4; i += 256) ((float4*)swl)[i] = wsrc[i];
    } else {
        constexpr int WQ = ICB * 9 / 4;
        for (int i = t; i < 16 * WQ; i += 256) {
            int ol = i / WQ, qi = i % WQ;
            ((float4*)swl)[ol * WQ + qi] =
                *(const float4*)(w + ((size_t)(ocg * 16 + ol) * IC + icc) * 9 + qi * 4);
        }
    }
    if (NORM_IN) __syncthreads();               // sNm ready before staging uses it

    // ---- stage input tile: 4 float4 + 1 halo scalar per (ic,row) ----
    int iy0 = ty * 16 - 1;
    int xbase = tx * 16;
    if (RESIZE_IN) {
        for (int q = t; q < ICB * 17 * 4; q += 256) {
            int ic_l = q / 68;
            int r2   = q % 68;
            int row  = r2 >> 2, quad = r2 & 3;
            int iy = iy0 + row;
            float4 v = {0.f, 0.f, 0.f, 0.f};
            if (iy >= 0 && iy < IH) {
                const float* lb_ = in + (size_t)(b * IC + icc + ic_l) * HW_IMG
                                      + (size_t)(4 * iy + 1) * 1024;
                int c0 = (xbase + quad * 4) * 4;          // 16B-aligned
                const float4* pa = (const float4*)(lb_ + c0);
                const float4* pb = (const float4*)(lb_ + 1024 + c0);
                float4 a0 = pa[0], a1 = pa[1], a2 = pa[2], a3 = pa[3];
                float4 q0 = pb[0], q1 = pb[1], q2 = pb[2], q3 = pb[3];
                v.x = 0.25f * (a0.y + a0.z + q0.y + q0.z);
                v.y = 0.25f * (a1.y + a1.z + q1.y + q1.z);
                v.z = 0.25f * (a2.y + a2.z + q2.y + q2.z);
                v.w = 0.25f * (a3.y + a3.z + q3.y + q3.z);
            }
            *(float4*)(sIn + ic_l * TSZ + row * TROW + 4 + quad * 4) = v;
        }
        for (int h = t; h < ICB * 17; h += 256) {
            int ic_l = h / 17, row = h % 17;
            int iy = iy0 + row, ix = xbase - 1;
            float v = 0.f;
            if (iy >= 0 && iy < IH && ix >= 0) {
                const float* lb_ = in + (size_t)(b * IC + icc + ic_l) * HW_IMG
                                      + (size_t)(4 * iy + 1) * 1024;
                float4 a = *(const float4*)(lb_ + ix * 4);
                float4 q0 = *(const float4*)(lb_ + 1024 + ix * 4);
                v = 0.25f * (a.y + a.z + q0.y + q0.z);
            }
            sIn[ic_l * TSZ + row * TROW + 3] = v;
        }
    } else {
        const float* inb = in + (size_t)(b * IC + icc) * (IH * IW);
        for (int q = t; q < ICB * 17 * 4; q += 256) {
            int ic_l = q / 68;
            int r2   = q % 68;
            int row  = r2 >> 2, quad = r2 & 3;
            int iy = iy0 + row;
            float4 v = {0.f, 0.f, 0.f, 0.f};
            if (iy >= 0 && iy < IH) {
                v = *(const float4*)(inb + (size_t)ic_l * (IH * IW)
                                         + (size_t)iy * IW + xbase + quad * 4);
                if (NORM_IN) {
                    float sc = sNm[(icc + ic_l) * 2], sh = sNm[(icc + ic_l) * 2 + 1];
                    v.x = v.x * sc + sh; v.y = v.y * sc + sh;
                    v.z = v.z * sc + sh; v.w = v.w * sc + sh;
                }
            }
            *(float4*)(sIn + ic_l * TSZ + row * TROW + 4 + quad * 4) = v;
        }
        for (int h = t; h < ICB * 17; h += 256) {
            int ic_l = h / 17, row = h % 17;
            int iy = iy0 + row, ix = xbase - 1;
            float v = 0.f;
            if (iy >= 0 && iy < IH && ix >= 0) {
                v = inb[(size_t)ic_l * (IH * IW) + (size_t)iy * IW + ix];
                if (NORM_IN) v = v * sNm[(icc + ic_l) * 2] + sNm[(icc + ic_l) * 2 + 1];
            }
            sIn[ic_l * TSZ + row * TROW + 3] = v;
        }
    }
    __syncthreads();

    // ---- compute ----
    float acc[4];
    #pragma unroll
    for (int j = 0; j < 4; j++) acc[j] = (NSPLIT == 1) ? bias[oc0 + j] : 0.f;

    for (int i2 = 0; i2 < ICB; i2++) {
        const float* tp = sIn + i2 * TSZ + py * 2 * TROW + pxx * 2 + 3;
        float x0 = tp[0],        x1 = tp[1],        x2 = tp[2];
        float x3 = tp[TROW],     x4 = tp[TROW + 1], x5 = tp[TROW + 2];
        float x6 = tp[2 * TROW], x7 = tp[2 * TROW + 1], x8 = tp[2 * TROW + 2];
        #pragma unroll
        for (int j = 0; j < 4; j++) {
            const float* wp = swl + ((lane * 4 + j) * ICB + i2) * 9;
            acc[j] = fmaf(x0, wp[0], acc[j]);
            acc[j] = fmaf(x1, wp[1], acc[j]);
            acc[j] = fmaf(x2, wp[2], acc[j]);
            acc[j] = fmaf(x3, wp[3], acc[j]);
            acc[j] = fmaf(x4, wp[4], acc[j]);
            acc[j] = fmaf(x5, wp[5], acc[j]);
            acc[j] = fmaf(x6, wp[6], acc[j]);
            acc[j] = fmaf(x7, wp[7], acc[j]);
            acc[j] = fmaf(x8, wp[8], acc[j]);
        }
    }

    int oy = ty * 8 + py, ox = tx * 8 + pxx;
    if (NSPLIT == 1) {
        int tile = ty * NTX + tx;
        #pragma unroll
        for (int j = 0; j < 4; j++) {
            float a = acc[j];
            a = a >= 0.f ? a : NEG * a;
            out[((size_t)(b * OC + oc0 + j) * OH + oy) * OW + ox] = a;
            if (STATS_OUT) {
                float s1 = a, s2 = a * a;
                for (int off = 32; off > 0; off >>= 1) {
                    s1 += __shfl_down(s1, off, 64);
                    s2 += __shfl_down(s2, off, 64);
                }
                if (px == 0) {
                    size_t pi = ((size_t)(b * OC + oc0 + j) * NT + tile) * 2;
                    part_out[pi] = s1; part_out[pi + 1] = s2;
                }
            }
        }
    } else {
        #pragma unroll
        for (int j = 0; j < 4; j++) {
            part_out[(size_t)icc_i * (BATCH * OC * PX) +
                     (size_t)(b * OC + oc0 + j) * PX + oy * OW + ox] = acc[j];
        }
    }
}

// ---------------- combine ic-split partials: + bias, LeakyReLU, optional stats -------------
template<int NSPLIT, int OC, int PX, bool STATS>
__global__ void k_combine(const float* __restrict__ ps, const float* __restrict__ bias,
                          float* __restrict__ out, float* __restrict__ spart) {
    constexpr int TOT = BATCH * OC * PX;
    int e = blockIdx.x * 256 + threadIdx.x;
    if (e >= TOT) return;
    float s = 0.f;
    #pragma unroll
    for (int k = 0; k < NSPLIT; k++) s += ps[(size_t)k * TOT + e];
    int oc = (e / PX) % OC;
    s += bias[oc];
    s = s >= 0.f ? s : NEG * s;
    out[e] = s;
    if (STATS) {
        float s1 = s, s2 = s * s;
        for (int off = 32; off > 0; off >>= 1) {
            s1 += __shfl_down(s1, off, 64);
            s2 += __shfl_down(s2, off, 64);
        }
        if ((threadIdx.x & 63) == 0) {
            int widx = e >> 6;
            spart[widx * 2] = s1; spart[widx * 2 + 1] = s2;
        }
    }
}

// ---------------- head: pool(f5) -> codes; weights; vertices; 5-float search table --------
// Table per (b,ch), 256 bins u (x*2^8 exact): entry {vs, m0, c0, m1, c1} at stride 5:
//   coord = (x < vs) ? m0*x+c0 : m1*x+c1   (exact when <=1 interior vertex per bin;
//   >=2 interior -> m0=NaN marker -> transform binary-search fallback).
__global__ void k_head(const float* __restrict__ f5, const float* __restrict__ lw,
                       const float* __restrict__ lb, const float* __restrict__ aw,
                       const float* __restrict__ ab, float* __restrict__ wt,
                       float* __restrict__ vert, float* __restrict__ gT,
                       float* __restrict__ out_w, float* __restrict__ out_v) {
    int blk = blockIdx.x;
    int t = threadIdx.x;  // 64 threads
    if (blk == 12) {
        __shared__ float sc2[2048];
        for (int s = t; s < 2048; s += 64) {
            int b = s >> 9, rest = s & 511, oc = rest >> 2, q = rest & 3;
            int py = (q >> 1) * 4, pxq = (q & 1) * 4;
            const float* p = f5 + (size_t)(b * 128 + oc) * 64;
            float sum = 0.f;
            #pragma unroll
            for (int dy = 0; dy < 4; dy++) {
                float4 v = *(const float4*)(p + (py + dy) * 8 + pxq);
                sum += v.x + v.y + v.z + v.w;
            }
            sc2[s] = sum * (1.f / 16.f);
        }
        __syncthreads();
        if (t < 48) {
            int j = t >> 2, q = t & 3;          // 12 outputs x 4 threads
            int b = j / 3, jj = j % 3;
            const float4* c4 = (const float4*)(sc2 + b * 512 + q * 128);
            const float4* l4 = (const float4*)(lw + jj * 512 + q * 128);
            float s = 0.f;
            for (int k = 0; k < 32; k++) {
                float4 cv = c4[k], lv = l4[k];
                s += cv.x * lv.x + cv.y * lv.y + cv.z * lv.z + cv.w * lv.w;
            }
            s += __shfl_down(s, 2, 64);
            s += __shfl_down(s, 1, 64);
            if (q == 0) { s += lb[jj]; wt[j] = s; out_w[j] = s; }
        }
        return;
    }
    int b = blk / 3, ch = blk % 3;
    __shared__ float scode[512];
    __shared__ float y[32];
    __shared__ float vsh[33];
    for (int s = t; s < 512; s += 64) {
        int oc = s >> 2, q = s & 3;
        int py = (q >> 1) * 4, pxq = (q & 1) * 4;
        const float* p = f5 + (size_t)(b * 128 + oc) * 64;
        float sum = 0.f;
        #pragma unroll
        for (int dy = 0; dy < 4; dy++) {
            float4 v = *(const float4*)(p + (py + dy) * 8 + pxq);
            sum += v.x + v.y + v.z + v.w;
        }
        scode[s] = sum * (1.f / 16.f);
    }
    __syncthreads();
    {   // logits: 32 outputs x 2 threads (k-halves), float4 loads
        int m = t & 31, half = t >> 5;
        const float4* c4 = (const float4*)(scode + half * 256);
        const float4* a4 = (const float4*)(aw + (size_t)(ch * 32 + m) * 512 + half * 256);
        float s = (half == 0) ? ab[ch * 32 + m] : 0.f;
        for (int k = 0; k < 64; k++) {
            float4 cv = c4[k], av = a4[k];
            s += cv.x * av.x + cv.y * av.y + cv.z * av.z + cv.w * av.w;
        }
        s += __shfl_down(s, 32, 64);
        if (half == 0) y[m] = s;
    }
    __syncthreads();
    if (t == 0) {
        float mx = y[0];
        for (int m = 1; m < 32; m++) mx = fmaxf(mx, y[m]);
        float e[32];
        float sum = 0.f;
        for (int m = 0; m < 32; m++) { e[m] = expf(y[m] - mx); sum += e[m]; }
        float inv = 1.f / sum;
        float cum = 0.f;
        float* vb = vert + (b * 3 + ch) * 33;
        float* ob = out_v + (b * 3 + ch) * 33;
        vb[0] = 0.f; ob[0] = 0.f; vsh[0] = 0.f;
        for (int m = 0; m < 32; m++) {
            cum += e[m] * inv;
            vb[m + 1] = cum; ob[m + 1] = cum; vsh[m + 1] = cum;
        }
    }
    __syncthreads();
    float* T = gT + (size_t)(b * 3 + ch) * 1280;
    for (int u = t; u < 256; u += 64) {
        float lo = (float)u * (1.f / 256.f);        // exact
        float hi = (float)(u + 1) * (1.f / 256.f);  // exact
        int n0 = 0, nin = 0;
        float vs = 2.0f;
        #pragma unroll
        for (int m = 0; m < 33; m++) {
            float vm = vsh[m];
            n0 += (vm <= lo) ? 1 : 0;
            if (vm > lo && vm < hi) { if (nin == 0) vs = vm; nin++; }
        }
        int i0 = n0 < 1 ? 1 : (n0 > 32 ? 32 : n0);
        int i1 = (n0 + 1) < 1 ? 1 : ((n0 + 1) > 32 ? 32 : (n0 + 1));
        float m0 = 1.f / (vsh[i0] - vsh[i0 - 1] + 1e-8f);
        float c0 = (float)(i0 - 1) - vsh[i0 - 1] * m0;
        float m1 = 1.f / (vsh[i1] - vsh[i1 - 1] + 1e-8f);
        float c1 = (float)(i1 - 1) - vsh[i1 - 1] * m1;
        if (nin >= 2) { vs = 2.0f; m0 = __int_as_float(0x7fc00000); c0 = 0.f; }
        T[u * 5]     = vs;
        T[u * 5 + 1] = m0;
        T[u * 5 + 2] = c0;
        T[u * 5 + 3] = m1;
        T[u * 5 + 4] = c1;
    }
}

// ---------------- fused LUT-gen + cell-gather, corner-parallel (4 thr/cell) ----------------
// Record (64B stride, 48B used) = 4 corners x 6 halves (r0,g0,b0,r1,g1,b1). Thread cg
// computes corner cg's 6 halves and writes 3 u32 words at record word-offset 3*cg:
// threads cg=0..3 of a cell write words 0..11 contiguously (word 12..15 unused).
__global__ void k_cells(const float* __restrict__ bw, const float* __restrict__ wtp,
                        unsigned int* __restrict__ cells) {
    int gid = blockIdx.x * 256 + threadIdx.x;     // 4*32768*4 = 524288
    if (gid >= BATCH * 32768 * 4) return;
    int cg   = gid & 3;
    int cell = (gid >> 2) & 32767;
    int b    = gid >> 17;
    int k0 = cell & 31, j0 = (cell >> 5) & 31, i0 = cell >> 10;
    float w0 = wtp[b * 3], w1 = wtp[b * 3 + 1], w2 = wtp[b * 3 + 2];
    int ii = i0 + (cg >> 1), jj = j0 + (cg & 1);
    int ci = (ii * 33 + jj) * 33 + k0;
    union { __half h[6]; unsigned int u[3]; } pk;
    #pragma unroll
    for (int kk = 0; kk < 2; kk++) {
        #pragma unroll
        for (int pl = 0; pl < 3; pl++) {
            const float* p = bw + ((size_t)(pl * LUT_D3 + ci + kk)) * 3;
            pk.h[kk * 3 + pl] = __float2half_rn(p[0] * w0 + p[1] * w1 + p[2] * w2);
        }
    }
    unsigned int* dst = cells + ((size_t)(b * 32768 + cell) << 4) + cg * 3;
    dst[0] = pk.u[0]; dst[1] = pk.u[1]; dst[2] = pk.u[2];
}

// ---------------- per-pixel linear-table search (stride-5 LDS, bank-spread) ----------------
__device__ __forceinline__ void searchL5(const float* __restrict__ T,
                                         const float* __restrict__ v33,
                                         float x, int& i0, float& f) {
    int u = (int)(x * 256.f);                   // exact floor (x*2^8 lossless)
    u = u < 0 ? 0 : (u > 255 ? 255 : u);
    const float* e = T + u * 5;                 // stride 5: banks 5u%32 cover all 32
    float vs = e[0];
    float coord = (x < vs) ? fmaf(e[1], x, e[2]) : fmaf(e[3], x, e[4]);
    if (!(coord == coord)) {                    // NaN marker: exact fallback (~never)
        int lo = 0, hi = LUT_D;
        while (lo < hi) { int mid = (lo + hi) >> 1; if (v33[mid] <= x) lo = mid + 1; else hi = mid; }
        int idx = lo < 1 ? 1 : (lo > LUT_D - 1 ? LUT_D - 1 : lo);
        float vl = v33[idx - 1], vh = v33[idx];
        coord = (float)(idx - 1) + (x - vl) / (vh - vl + 1e-8f);
    }
    coord = fminf(fmaxf(coord, 0.f), (float)(LUT_D - 1));
    i0 = (int)coord;
    if (i0 > LUT_D - 2) i0 = LUT_D - 2;
    f = coord - (float)i0;
}

// decode one corner (3 packed fp16 words = r0,g0,b0,r1,g1,b1), lerp along blue
__device__ __forceinline__ void decode_lerp3(float wa, float wb, float wc, float fb,
                                             float& rv, float& gv, float& bv) {
    union { float f; __half2 h; } u0, u1, u2;
    u0.f = wa; u1.f = wb; u2.f = wc;
    float2 a = __half22float2(u0.h);   // r0, g0
    float2 b = __half22float2(u1.h);   // b0, r1
    float2 c = __half22float2(u2.h);   // g1, b1
    rv = fmaf(fb, b.y - a.x, a.x);
    gv = fmaf(fb, c.x - a.y, a.y);
    bv = fmaf(fb, c.y - b.x, b.x);
}

__global__ void __launch_bounds__(256) k_transform(const float* __restrict__ lq,
                                                   const float4* __restrict__ cells,
                                                   const float* __restrict__ vert,
                                                   const float* __restrict__ gT,
                                                   float* __restrict__ out) {
    // XCD-aware remap: 2 XCDs per image -> each XCD's L2 holds one image's 2MB cells.
    // Bijective for grid 4096 (4 px/thread).
    int orig = blockIdx.x;
    int xcd  = orig & 7;
    int bimg = xcd >> 1;
    int blk  = ((orig >> 3) << 1) | (xcd & 1);    // [0,1024)

    __shared__ float sT[3840];                    // 3 ch * 256 bins * 5
    __shared__ float sv[100];

    // issue pixel loads before the staging barrier (independent of LDS)
    int p0 = blk * 1024 + threadIdx.x * 4;        // 4 px per thread
    const float* lr = lq + (size_t)bimg * 3 * HW_IMG + p0;
    float4 r4 = *(const float4*)(lr);
    float4 g4 = *(const float4*)(lr + HW_IMG);
    float4 b4 = *(const float4*)(lr + 2 * HW_IMG);

    for (int i = threadIdx.x; i < 3840; i += 256) sT[i] = gT[bimg * 3840 + i];
    if (threadIdx.x < 99) sv[threadIdx.x] = vert[bimg * 99 + threadIdx.x];
    __syncthreads();

    float rr[4] = {r4.x, r4.y, r4.z, r4.w};
    float gg[4] = {g4.x, g4.y, g4.z, g4.w};
    float bb[4] = {b4.x, b4.y, b4.z, b4.w};

    // phase 1: 12 independent flat searches
    int cidx[4];
    float fra[4], fga[4], fba[4];
    #pragma unroll
    for (int i = 0; i < 4; i++) {
        int i0, j0, k0;
        searchL5(sT,        sv,      rr[i], i0, fra[i]);
        searchL5(sT + 1280, sv + 33, gg[i], j0, fga[i]);
        searchL5(sT + 2560, sv + 66, bb[i], k0, fba[i]);
        cidx[i] = ((i0 * 32 + j0) << 5) + k0;
    }
    // phase 2: issue all cell loads (4 independent lines -> max MLP)
    float4 c0[4], c1[4], c2[4];
    #pragma unroll
    for (int i = 0; i < 4; i++) {
        const float4* p = cells + (((size_t)(bimg << 15) + cidx[i]) << 2);
        c0[i] = p[0]; c1[i] = p[1]; c2[i] = p[2];
    }
    // phase 3: decode + bilinear blend
    float ro[4], go[4], bo[4];
    #pragma unroll
    for (int i = 0; i < 4; i++) {
        float fb = fba[i];
        float r00, g00, b00, r01, g01, b01, r10, g10, b10, r11, g11, b11;
        decode_lerp3(c0[i].x, c0[i].y, c0[i].z, fb, r00, g00, b00);
        decode_lerp3(c0[i].w, c1[i].x, c1[i].y, fb, r01, g01, b01);
        decode_lerp3(c1[i].z, c1[i].w, c2[i].x, fb, r10, g10, b10);
        decode_lerp3(c2[i].y, c2[i].z, c2[i].w, fb, r11, g11, b11);
        float fr = fra[i], fg = fga[i];
        float w00 = (1.f - fr) * (1.f - fg), w01 = (1.f - fr) * fg;
        float w10 = fr * (1.f - fg),         w11 = fr * fg;
        float rx = r00 * w00 + r01 * w01 + r10 * w10 + r11 * w11;
        float ry = g00 * w00 + g01 * w01 + g10 * w10 + g11 * w11;
        float rz = b00 * w00 + b01 * w01 + b10 * w10 + b11 * w11;
        ro[i] = fminf(fmaxf(rx, 0.f), 1.f);
        go[i] = fminf(fmaxf(ry, 0.f), 1.f);
        bo[i] = fminf(fmaxf(rz, 0.f), 1.f);
    }
    float* op = out + (size_t)bimg * 3 * HW_IMG + p0;
    *(float4*)(op)              = make_float4(ro[0], ro[1], ro[2], ro[3]);
    *(float4*)(op + HW_IMG)     = make_float4(go[0], go[1], go[2], go[3]);
    *(float4*)(op + 2 * HW_IMG) = make_float4(bo[0], bo[1], bo[2], bo[3]);
}

extern "C" void kernel_launch(void* const* d_in, const int* in_sizes, int n_in,
                              void* d_out, int out_size, void* d_ws, size_t ws_size,
                              hipStream_t stream) {
    const float* lq  = (const float*)d_in[0];
    const float* w1  = (const float*)d_in[1];
    const float* b1  = (const float*)d_in[2];
    const float* g1  = (const float*)d_in[3];
    const float* be1 = (const float*)d_in[4];
    const float* w2  = (const float*)d_in[5];
    const float* b2  = (const float*)d_in[6];
    const float* g2  = (const float*)d_in[7];
    const float* be2 = (const float*)d_in[8];
    const float* w3  = (const float*)d_in[9];
    const float* b3  = (const float*)d_in[10];
    const float* g3  = (const float*)d_in[11];
    const float* be3 = (const float*)d_in[12];
    const float* w4  = (const float*)d_in[13];
    const float* b4  = (const float*)d_in[14];
    const float* g4  = (const float*)d_in[15];
    const float* be4 = (const float*)d_in[16];
    const float* w5  = (const float*)d_in[17];
    const float* b5  = (const float*)d_in[18];
    const float* lw  = (const float*)d_in[19];
    const float* lb  = (const float*)d_in[20];
    const float* bw  = (const float*)d_in[21];
    const float* aw  = (const float*)d_in[22];
    const float* ab  = (const float*)d_in[23];

    // Workspace: cells (2,097,152 floats) aliases f1..f5 (dead before k_cells).
    // psplit4/5 alias f1 (dead after S2). Tail region disjoint.
    float* ws    = (float*)d_ws;
    float* cells = ws;                     // 4*32768 cells * 16 floats = 2,097,152
    float* f1    = ws;                     // 1,048,576  [4,16,128,128]
    float* f2    = f1 + 1048576;           //   524,288  [4,32,64,64]
    float* f3    = f2 + 524288;            //   262,144  [4,64,32,32]
    float* f4    = f3 + 262144;            //   131,072  [4,128,16,16]
    float* f5    = f4 + 131072;            //    32,768  [4,128,8,8]  (ends 1,998,848)
    float* psplit4 = f1;                   // 4*131072 = 524,288 (alias; f1 dead by S4)
    float* psplit5 = f1 + 524288;          // 8*32768  = 262,144
    float* tail  = ws + 2097152;
    float* wt    = tail;                   // 12
    float* vert  = wt + 12;                // 396
    float* part1 = vert + 396;             // 4*16*256*2  = 32,768
    float* part2 = part1 + 32768;          // 4*32*64*2   = 16,384
    float* part3 = part2 + 16384;          // 4*64*16*2   =  8,192
    float* part4 = part3 + 8192;           // 4*128*4*2   =  4,096
    float* gT    = part4 + 4096;           // 12 * 256 * 5 = 15,360

    float* outs  = (float*)d_out;
    float* out_w = outs + (size_t)BATCH * 3 * HW_IMG;  // 12582912
    float* out_v = out_w + 12;

    // S1: lq (fused resize) -> f1 [4,16,128,128]; grid 4*16*16*1 = 1024
    k_conv2<3, 16, 128, 128, 1, false, true, true><<<1024, 256, 0, stream>>>(
        lq, nullptr, nullptr, nullptr, 0.f, 0, w1, b1, f1, part1);
    // S2: f1 -> f2 [4,32,64,64]; fused IN from part1; grid 4*8*8*2 = 512
    k_conv2<16, 32, 64, 64, 1, true, false, true><<<512, 256, 0, stream>>>(
        f1, part1, g1, be1, 1.f / 16384.f, 256, w2, b2, f2, part2);
    // S3: f2 -> f3 [4,64,32,32]; fused IN from part2; grid 4*4*4*4 = 256
    k_conv2<32, 64, 32, 32, 1, true, false, true><<<256, 256, 0, stream>>>(
        f2, part2, g2, be2, 1.f / 4096.f, 64, w3, b3, f3, part3);
    // S4: f3 -> psplit4 (ic-split x4); grid 4*2*2*4*8 = 512; combine -> f4 + stats
    k_conv2<64, 128, 16, 16, 4, true, false, false><<<512, 256, 0, stream>>>(
        f3, part3, g3, be3, 1.f / 1024.f, 16, w4, b4, nullptr, psplit4);
    k_combine<4, 128, 256, true><<<512, 256, 0, stream>>>(psplit4, b4, f4, part4);
    // S5: f4 -> psplit5 (ic-split x8); grid 4*1*1*8*8 = 256; combine -> f5
    k_conv2<128, 128, 8, 8, 8, true, false, false><<<256, 256, 0, stream>>>(
        f4, part4, g4, be4, 1.f / 256.f, 4, w5, b5, nullptr, psplit5);
    k_combine<8, 128, 64, false><<<128, 256, 0, stream>>>(psplit5, b5, f5, nullptr);
    // head: pool + weights + vertices + search table
    k_head<<<13, 64, 0, stream>>>(f5, lw, lb, aw, ab, wt, vert, gT, out_w, out_v);
    // fused lutgen+cellgen, corner-parallel (4 threads per cell)
    k_cells<<<2048, 256, 0, stream>>>(bw, wt, (unsigned int*)cells);
    // transform: 4 px/thread, grid 4096
    k_transform<<<4096, 256, 0, stream>>>(lq, (const float4*)cells, vert, gT, outs);
}